// Round 6
// baseline (350.653 us; speedup 1.0000x reference)
//
#include <hip/hip_runtime.h>
#include <cstddef>
#include <cstdint>

#define QLEN   1024
#define SCALE  0.125f
#define LN_EPS 1e-5f
#define DMODEL 1024

typedef __bf16 bf16x8 __attribute__((ext_vector_type(8)));
typedef __bf16 bf16x4 __attribute__((ext_vector_type(4)));
typedef float  f32x4  __attribute__((ext_vector_type(4)));

__device__ __forceinline__ void load16_lds(const void* g, void* l) {
  __builtin_amdgcn_global_load_lds(
      (const __attribute__((address_space(1))) unsigned int*)g,
      (__attribute__((address_space(3))) unsigned int*)l, 16, 0, 0);
}

// ---------------------------------------------------------------------------
// One cast kernel for all five fp32->bf16 inputs (block-range partitioned).
// ---------------------------------------------------------------------------
__global__ __launch_bounds__(256) void cast_all(
    const float* __restrict__ w, __bf16* __restrict__ w_bf,
    const float* __restrict__ Wqkv, __bf16* __restrict__ Wqkv_bf,
    const float* __restrict__ r, __bf16* __restrict__ r_bf,
    const float* __restrict__ Wr, __bf16* __restrict__ Wr_bf,
    const float* __restrict__ Wo, __bf16* __restrict__ Wo_bf)
{
  int blk = blockIdx.x;
  const float* in; __bf16* out;
  if (blk < 2048)      { in = w;    out = w_bf;    }
  else if (blk < 2688) { blk -= 2048; in = Wqkv; out = Wqkv_bf; }
  else if (blk < 3200) { blk -= 2688; in = r;    out = r_bf;    }
  else if (blk < 3264) { blk -= 3200; in = Wr;   out = Wr_bf;   }
  else                 { blk -= 3264; in = Wo;   out = Wo_bf;   }
  const size_t i = ((size_t)blk * 256 + threadIdx.x) * 8;
  const float4 a = *(const float4*)&in[i];
  const float4 b = *(const float4*)&in[i + 4];
  bf16x8 o;
  o[0] = (__bf16)a.x; o[1] = (__bf16)a.y; o[2] = (__bf16)a.z; o[3] = (__bf16)a.w;
  o[4] = (__bf16)b.x; o[5] = (__bf16)b.y; o[6] = (__bf16)b.z; o[7] = (__bf16)b.w;
  *(bf16x8*)&out[i] = o;
}

// ---------------------------------------------------------------------------
// QKV GEMM with fused scatter-epilogue: [4096,1280] = w_bf @ Wqkv_bf^T.
// wh never materializes: Q cols -> Qw/Qr (biases folded), K cols -> Kb,
// V cols -> Vt transposed. Row = i*4+b. grid (10, 32).
// ---------------------------------------------------------------------------
__global__ __launch_bounds__(256) void gemm_qkv(
    const __bf16* __restrict__ A, const __bf16* __restrict__ B,
    const float* __restrict__ rwb, const float* __restrict__ rrb,
    __bf16* __restrict__ Qw, __bf16* __restrict__ Qr,
    __bf16* __restrict__ Kb, __bf16* __restrict__ Vt)
{
  __shared__ __bf16 Asl[128 * 32];
  __shared__ __bf16 Bsl[128 * 32];
  const int tid  = threadIdx.x;
  const int lane = tid & 63;
  const int wv   = tid >> 6;
  const int m0 = blockIdx.y * 128;
  const int n0 = blockIdx.x * 128;
  const int wm = (wv >> 1) * 64;
  const int wn = (wv & 1) * 64;
  const int lr = lane & 15;
  const int kq = lane >> 4;

  const int srow  = wv * 16 + (lane >> 2);
  const int sslot = lane & 3;
  const int sg0 = (sslot - ((srow >> 1) & 3)) & 3;
  const int sg1 = (sslot - (((srow + 64) >> 1) & 3)) & 3;
  const __bf16* Ag = A + (size_t)(m0 + srow) * 1024;
  const __bf16* Bg = B + (size_t)(n0 + srow) * 1024;
  __bf16* Al = &Asl[srow * 32 + sslot * 8];
  __bf16* Bl = &Bsl[srow * 32 + sslot * 8];

  f32x4 acc[4][4];
#pragma unroll
  for (int mt = 0; mt < 4; ++mt)
#pragma unroll
    for (int nt = 0; nt < 4; ++nt)
      acc[mt][nt] = (f32x4){0.f, 0.f, 0.f, 0.f};

  for (int k0 = 0; k0 < 1024; k0 += 32) {
    load16_lds(Ag + k0 + sg0 * 8, Al);
    load16_lds(Ag + (size_t)64 * 1024 + k0 + sg1 * 8, Al + 64 * 32);
    load16_lds(Bg + k0 + sg0 * 8, Bl);
    load16_lds(Bg + (size_t)64 * 1024 + k0 + sg1 * 8, Bl + 64 * 32);
    __syncthreads();
    bf16x8 af[4], bfr[4];
#pragma unroll
    for (int mt = 0; mt < 4; ++mt) {
      const int row = wm + mt * 16 + lr;
      af[mt] = *(const bf16x8*)&Asl[row * 32 + ((kq + (row >> 1)) & 3) * 8];
    }
#pragma unroll
    for (int nt = 0; nt < 4; ++nt) {
      const int row = wn + nt * 16 + lr;
      bfr[nt] = *(const bf16x8*)&Bsl[row * 32 + ((kq + (row >> 1)) & 3) * 8];
    }
#pragma unroll
    for (int mt = 0; mt < 4; ++mt)
#pragma unroll
      for (int nt = 0; nt < 4; ++nt)
        acc[mt][nt] = __builtin_amdgcn_mfma_f32_16x16x32_bf16(
            af[mt], bfr[nt], acc[mt][nt], 0, 0, 0);
    __syncthreads();
  }

#pragma unroll
  for (int mt = 0; mt < 4; ++mt) {
    const int row0 = m0 + wm + mt * 16 + kq * 4;
#pragma unroll
    for (int nt = 0; nt < 4; ++nt) {
      const int gcol = n0 + wn + nt * 16 + lr;
      const f32x4 c = acc[mt][nt];
      if (n0 == 0) {            // Q region
        const int g = gcol >> 6, d = gcol & 63;
        const float bw = rwb[gcol], br = rrb[gcol];
#pragma unroll
        for (int reg = 0; reg < 4; ++reg) {
          const int row = row0 + reg, i = row >> 2, b = row & 3;
          const size_t o = (size_t)(b * 2 + g) * 65536 + (size_t)i * 64 + d;
          Qw[o] = (__bf16)(c[reg] + bw);
          Qr[o] = (__bf16)(c[reg] + br);
        }
      } else if (n0 == 128) {   // K region
        const int lc = gcol - 128, g = lc >> 6, d = lc & 63;
#pragma unroll
        for (int reg = 0; reg < 4; ++reg) {
          const int row = row0 + reg, i = row >> 2, b = row & 3;
          Kb[(size_t)(b * 2 + g) * 65536 + (size_t)i * 64 + d] = (__bf16)c[reg];
        }
      } else {                  // V region -> transposed Vt
        const int lc = gcol - 256, h = lc >> 6, d = lc & 63;
#pragma unroll
        for (int reg = 0; reg < 4; ++reg) {
          const int row = row0 + reg, i = row >> 2, b = row & 3;
          Vt[((size_t)((b * 16 + h) * 64 + d)) * 1024 + i] = (__bf16)c[reg];
        }
      }
    }
  }
}

// ---------------------------------------------------------------------------
// r GEMM with fused epilogue: [1024,128] = r_bf @ Wr_bf^T -> Rb[g][i][64].
// grid (1, 8).
// ---------------------------------------------------------------------------
__global__ __launch_bounds__(256) void gemm_r(
    const __bf16* __restrict__ A, const __bf16* __restrict__ B,
    __bf16* __restrict__ Rb)
{
  __shared__ __bf16 Asl[128 * 32];
  __shared__ __bf16 Bsl[128 * 32];
  const int tid  = threadIdx.x;
  const int lane = tid & 63;
  const int wv   = tid >> 6;
  const int m0 = blockIdx.y * 128;
  const int wm = (wv >> 1) * 64;
  const int wn = (wv & 1) * 64;
  const int lr = lane & 15;
  const int kq = lane >> 4;

  const int srow  = wv * 16 + (lane >> 2);
  const int sslot = lane & 3;
  const int sg0 = (sslot - ((srow >> 1) & 3)) & 3;
  const int sg1 = (sslot - (((srow + 64) >> 1) & 3)) & 3;
  const __bf16* Ag = A + (size_t)(m0 + srow) * 1024;
  const __bf16* Bg = B + (size_t)srow * 1024;
  __bf16* Al = &Asl[srow * 32 + sslot * 8];
  __bf16* Bl = &Bsl[srow * 32 + sslot * 8];

  f32x4 acc[4][4];
#pragma unroll
  for (int mt = 0; mt < 4; ++mt)
#pragma unroll
    for (int nt = 0; nt < 4; ++nt)
      acc[mt][nt] = (f32x4){0.f, 0.f, 0.f, 0.f};

  for (int k0 = 0; k0 < 1024; k0 += 32) {
    load16_lds(Ag + k0 + sg0 * 8, Al);
    load16_lds(Ag + (size_t)64 * 1024 + k0 + sg1 * 8, Al + 64 * 32);
    load16_lds(Bg + k0 + sg0 * 8, Bl);
    load16_lds(Bg + (size_t)64 * 1024 + k0 + sg1 * 8, Bl + 64 * 32);
    __syncthreads();
    bf16x8 af[4], bfr[4];
#pragma unroll
    for (int mt = 0; mt < 4; ++mt) {
      const int row = wm + mt * 16 + lr;
      af[mt] = *(const bf16x8*)&Asl[row * 32 + ((kq + (row >> 1)) & 3) * 8];
    }
#pragma unroll
    for (int nt = 0; nt < 4; ++nt) {
      const int row = wn + nt * 16 + lr;
      bfr[nt] = *(const bf16x8*)&Bsl[row * 32 + ((kq + (row >> 1)) & 3) * 8];
    }
#pragma unroll
    for (int mt = 0; mt < 4; ++mt)
#pragma unroll
      for (int nt = 0; nt < 4; ++nt)
        acc[mt][nt] = __builtin_amdgcn_mfma_f32_16x16x32_bf16(
            af[mt], bfr[nt], acc[mt][nt], 0, 0, 0);
    __syncthreads();
  }

#pragma unroll
  for (int mt = 0; mt < 4; ++mt) {
    const int row0 = m0 + wm + mt * 16 + kq * 4;
#pragma unroll
    for (int nt = 0; nt < 4; ++nt) {
      const int gcol = wn + nt * 16 + lr;
      const int g = gcol >> 6, d = gcol & 63;
      const f32x4 c = acc[mt][nt];
#pragma unroll
      for (int reg = 0; reg < 4; ++reg)
        Rb[(size_t)g * 65536 + (size_t)(row0 + reg) * 64 + d] = (__bf16)c[reg];
    }
  }
}

// ---------------------------------------------------------------------------
// Generic bf16 MFMA GEMM (kept for Wo projection).
// ---------------------------------------------------------------------------
template<typename OutT>
__global__ __launch_bounds__(256) void gemm_bf16(
    const __bf16* __restrict__ A, const __bf16* __restrict__ B,
    OutT* __restrict__ C, int K, int lda, int ldb, int ldc)
{
  __shared__ __bf16 Asl[128 * 32];
  __shared__ __bf16 Bsl[128 * 32];
  const int tid  = threadIdx.x;
  const int lane = tid & 63;
  const int wv   = tid >> 6;
  const int m0 = blockIdx.y * 128;
  const int n0 = blockIdx.x * 128;
  const int wm = (wv >> 1) * 64;
  const int wn = (wv & 1) * 64;
  const int lr = lane & 15;
  const int kq = lane >> 4;

  const int srow  = wv * 16 + (lane >> 2);
  const int sslot = lane & 3;
  const int sg0 = (sslot - ((srow >> 1) & 3)) & 3;
  const int sg1 = (sslot - (((srow + 64) >> 1) & 3)) & 3;
  const __bf16* Ag = A + (size_t)(m0 + srow) * lda;
  const __bf16* Bg = B + (size_t)(n0 + srow) * ldb;
  __bf16* Al = &Asl[srow * 32 + sslot * 8];
  __bf16* Bl = &Bsl[srow * 32 + sslot * 8];

  f32x4 acc[4][4];
#pragma unroll
  for (int mt = 0; mt < 4; ++mt)
#pragma unroll
    for (int nt = 0; nt < 4; ++nt)
      acc[mt][nt] = (f32x4){0.f, 0.f, 0.f, 0.f};

  for (int k0 = 0; k0 < K; k0 += 32) {
    load16_lds(Ag + k0 + sg0 * 8, Al);
    load16_lds(Ag + (size_t)64 * lda + k0 + sg1 * 8, Al + 64 * 32);
    load16_lds(Bg + k0 + sg0 * 8, Bl);
    load16_lds(Bg + (size_t)64 * ldb + k0 + sg1 * 8, Bl + 64 * 32);
    __syncthreads();
    bf16x8 af[4], bfr[4];
#pragma unroll
    for (int mt = 0; mt < 4; ++mt) {
      const int row = wm + mt * 16 + lr;
      af[mt] = *(const bf16x8*)&Asl[row * 32 + ((kq + (row >> 1)) & 3) * 8];
    }
#pragma unroll
    for (int nt = 0; nt < 4; ++nt) {
      const int row = wn + nt * 16 + lr;
      bfr[nt] = *(const bf16x8*)&Bsl[row * 32 + ((kq + (row >> 1)) & 3) * 8];
    }
#pragma unroll
    for (int mt = 0; mt < 4; ++mt)
#pragma unroll
      for (int nt = 0; nt < 4; ++nt)
        acc[mt][nt] = __builtin_amdgcn_mfma_f32_16x16x32_bf16(
            af[mt], bfr[nt], acc[mt][nt], 0, 0, 0);
    __syncthreads();
  }

#pragma unroll
  for (int mt = 0; mt < 4; ++mt) {
    const int row0 = m0 + wm + mt * 16 + kq * 4;
#pragma unroll
    for (int nt = 0; nt < 4; ++nt) {
      const int col = n0 + wn + nt * 16 + lr;
      const f32x4 c = acc[mt][nt];
#pragma unroll
      for (int reg = 0; reg < 4; ++reg)
        C[(size_t)(row0 + reg) * ldc + col] = (OutT)c[reg];
    }
  }
}

// ---------------------------------------------------------------------------
// Batched K=64 bf16 MFMA GEMM for AC/BD. Rb indexed by g only.
// ---------------------------------------------------------------------------
__global__ __launch_bounds__(256) void gemm64_bf16(
    const __bf16* __restrict__ Qw, const __bf16* __restrict__ Qr,
    const __bf16* __restrict__ Kb, const __bf16* __restrict__ Rb,
    __bf16* __restrict__ AC, __bf16* __restrict__ BDo)
{
  __shared__ __bf16 Asl[128 * 64];
  __shared__ __bf16 Bsl[128 * 64];
  const int tid = threadIdx.x, lane = tid & 63, wv = tid >> 6;
  const int which = blockIdx.z & 1, bat = blockIdx.z >> 1;
  const int m0 = blockIdx.y * 128, n0 = blockIdx.x * 128;
  const __bf16* Ap = (which ? Qr : Qw) + (size_t)bat * 65536;
  const __bf16* Bp = which ? (Rb + (size_t)(bat & 1) * 65536)
                           : (Kb + (size_t)bat * 65536);
  __bf16* Cp = (which ? BDo : AC) + (size_t)bat * 1048576;

#pragma unroll
  for (int p = 0; p < 4; ++p) {
    const int row = wv * 32 + p * 8 + (lane >> 3);
    const int s = lane & 7;
    const int gc = (s - (row & 7)) & 7;
    load16_lds(Ap + (size_t)(m0 + row) * 64 + gc * 8, &Asl[row * 64 + s * 8]);
    load16_lds(Bp + (size_t)(n0 + row) * 64 + gc * 8, &Bsl[row * 64 + s * 8]);
  }
  __syncthreads();

  const int lr = lane & 15, kq = lane >> 4;
  const int wm = (wv >> 1) * 64, wn = (wv & 1) * 64;
  f32x4 acc[4][4];
#pragma unroll
  for (int mt = 0; mt < 4; ++mt)
#pragma unroll
    for (int nt = 0; nt < 4; ++nt)
      acc[mt][nt] = (f32x4){0.f, 0.f, 0.f, 0.f};

#pragma unroll
  for (int ks = 0; ks < 2; ++ks) {
    const int c = ks * 4 + kq;
    bf16x8 af[4], bfr[4];
#pragma unroll
    for (int mt = 0; mt < 4; ++mt) {
      const int row = wm + mt * 16 + lr;
      af[mt] = *(const bf16x8*)&Asl[row * 64 + ((c + (row & 7)) & 7) * 8];
    }
#pragma unroll
    for (int nt = 0; nt < 4; ++nt) {
      const int row = wn + nt * 16 + lr;
      bfr[nt] = *(const bf16x8*)&Bsl[row * 64 + ((c + (row & 7)) & 7) * 8];
    }
#pragma unroll
    for (int mt = 0; mt < 4; ++mt)
#pragma unroll
      for (int nt = 0; nt < 4; ++nt)
        acc[mt][nt] = __builtin_amdgcn_mfma_f32_16x16x32_bf16(
            af[mt], bfr[nt], acc[mt][nt], 0, 0, 0);
  }

#pragma unroll
  for (int mt = 0; mt < 4; ++mt) {
    const int row0 = m0 + wm + mt * 16 + kq * 4;
#pragma unroll
    for (int nt = 0; nt < 4; ++nt) {
      const int col = n0 + wn + nt * 16 + lr;
      const f32x4 cc = acc[mt][nt];
#pragma unroll
      for (int reg = 0; reg < 4; ++reg)
        Cp[(size_t)(row0 + reg) * 1024 + col] = (__bf16)cc[reg];
    }
  }
}

// ---------------------------------------------------------------------------
// prep2: blocks [0,2048) = tshift (T = (AC+BDshift)*SCALE),
//        blocks [2048,3072) = per-head mixed masks Mh.
// ---------------------------------------------------------------------------
__global__ __launch_bounds__(256) void prep2(
    const __bf16* __restrict__ AC, const __bf16* __restrict__ BDm,
    __bf16* __restrict__ Tg,
    const float* __restrict__ masks, const float* __restrict__ mproj,
    __bf16* __restrict__ Mh)
{
  const int tid = threadIdx.x;
  if (blockIdx.x < 2048) {
    const int blk = blockIdx.x;
    const size_t bg = blk >> 8;
    const int i = (blk & 255) * 4 + (tid >> 6);
    const int lane = tid & 63;
    const __bf16* ACr = AC + bg * 1048576 + (size_t)i * 1024;
    const __bf16* BDb = BDm + bg * 1048576;
    __bf16* Tr = Tg + bg * 1048576 + (size_t)i * 1024;
#pragma unroll
    for (int c2 = 0; c2 < 4; ++c2) {
      const int j0 = c2 * 256 + lane * 4;
      const bf16x4 ac4 = *(const bf16x4*)&ACr[j0];
      bf16x4 o;
#pragma unroll
      for (int k = 0; k < 4; ++k) {
        const int j = j0 + k;
        float bd;
        if (j <= i)          bd = (float)BDb[(size_t)i * 1024 + (j + QLEN - 1 - i)];
        else if (j == i + 1) bd = 0.f;
        else                 bd = (float)BDb[(size_t)(i + 1) * 1024 + (j - i - 2)];
        o[k] = (__bf16)(((float)ac4[k] + bd) * SCALE);
      }
      *(bf16x4*)&Tr[j0] = o;
    }
  } else {
    const int blk = blockIdx.x - 2048;
    const size_t ij0 = ((size_t)blk * 256 + tid) * 4;
    const float4 a = *(const float4*)&masks[ij0 * 3];
    const float4 b = *(const float4*)&masks[ij0 * 3 + 4];
    const float4 c = *(const float4*)&masks[ij0 * 3 + 8];
    const float m0[4] = {a.x, a.w, b.z, c.y};
    const float m1[4] = {a.y, b.x, b.w, c.z};
    const float m2[4] = {a.z, b.y, c.x, c.w};
#pragma unroll
    for (int h = 0; h < 16; ++h) {
      const float p0 = mproj[h], p1 = mproj[16 + h], p2 = mproj[32 + h];
      bf16x4 o;
#pragma unroll
      for (int k = 0; k < 4; ++k)
        o[k] = (__bf16)(m0[k] * p0 + m1[k] * p1 + m2[k] * p2);
      *(bf16x4*)&Mh[(size_t)h * 1048576 + ij0] = o;
    }
  }
}

// ---------------------------------------------------------------------------
// attn5: 512 threads (8 waves), 16-row tile -> 32 KB LDS, 4 blk/CU x 8 waves
// = 100% occupancy. Score pass single-pass (no max; |s|<=~8). PV: 8 waves x
// 8 d-cols each (lanes m>=8 duplicate m&7 -> broadcast; store only m<8).
// grid (64, 16, 4).
// ---------------------------------------------------------------------------
__global__ __launch_bounds__(512, 8) void attn5(
    const __bf16* __restrict__ Tg, const __bf16* __restrict__ Mh,
    const __bf16* __restrict__ Vt, __bf16* __restrict__ av)
{
  __shared__ __bf16 P[16 * 1024];
  __shared__ float rinvS[16];
  const int tid = threadIdx.x;
  const int i0 = blockIdx.x * 16;
  const int h = blockIdx.y, b = blockIdx.z;
  const int g = h >> 3;
  const size_t bg = (size_t)(b * 2 + g);
  const int r = tid >> 5, li = tid & 31;
  const __bf16* Trow = Tg + bg * 1048576 + (size_t)(i0 + r) * 1024;
  const __bf16* Mrow = Mh + (size_t)h * 1048576 + (size_t)(i0 + r) * 1024;

  float sum = 0.f;
#pragma unroll
  for (int q = 0; q < 4; ++q) {
    const int jb = q * 256 + li * 8;
    const bf16x8 t8 = *(const bf16x8*)&Trow[jb];
    const bf16x8 m8 = *(const bf16x8*)&Mrow[jb];
    const int csw = (jb >> 3) ^ (r & 7);
    bf16x8 p8;
#pragma unroll
    for (int k = 0; k < 8; ++k) {
      const float e = __expf((float)t8[k] * (float)m8[k]);
      sum += e;
      p8[k] = (__bf16)e;
    }
    *(bf16x8*)&P[r * 1024 + csw * 8] = p8;
  }
  sum += __shfl_xor(sum, 1);
  sum += __shfl_xor(sum, 2);
  sum += __shfl_xor(sum, 4);
  sum += __shfl_xor(sum, 8);
  sum += __shfl_xor(sum, 16);
  if (li == 0) rinvS[r] = 1.f / sum;
  __syncthreads();

  const int lane = tid & 63, wv = tid >> 6;
  const int m = lane & 15, kq = lane >> 4;
  const int d = wv * 8 + (m & 7);
  const __bf16* vbase = Vt + ((size_t)((b * 16 + h) * 64 + d)) * 1024 + kq * 8;
  f32x4 acc = (f32x4){0.f, 0.f, 0.f, 0.f};
#pragma unroll 8
  for (int ks = 0; ks < 32; ++ks) {
    const int c = ks * 4 + kq;
    const bf16x8 a = *(const bf16x8*)&P[m * 1024 + ((c ^ (m & 7)) << 3)];
    const bf16x8 vv = *(const bf16x8*)&vbase[ks * 32];
    acc = __builtin_amdgcn_mfma_f32_16x16x32_bf16(a, vv, acc, 0, 0, 0);
  }
  if (m < 8) {
#pragma unroll
    for (int reg = 0; reg < 4; ++reg) {
      const int row = kq * 4 + reg;
      av[((size_t)(i0 + row) * 4 + b) * 1024 + h * 64 + d] =
          (__bf16)(acc[reg] * rinvS[row]);
    }
  }
}

// ---------------------------------------------------------------------------
// residual + LayerNorm
// ---------------------------------------------------------------------------
__global__ __launch_bounds__(256) void ln_kernel(
    const float* __restrict__ w, const float* __restrict__ ao,
    const float* __restrict__ gamma, const float* __restrict__ beta,
    float* __restrict__ out)
{
  const int tid = threadIdx.x;
  const size_t base = (size_t)blockIdx.x * DMODEL;
  __shared__ float red[256];
  float x[4];
  float s = 0.f;
#pragma unroll
  for (int p = 0; p < 4; ++p) {
    const int c = tid + p * 256;
    x[p] = w[base + c] + ao[base + c];
    s += x[p];
  }
  red[tid] = s; __syncthreads();
  for (int off = 128; off > 0; off >>= 1) {
    if (tid < off) red[tid] += red[tid + off];
    __syncthreads();
  }
  const float mu = red[0] * (1.f / DMODEL);
  __syncthreads();
  float s2 = 0.f;
#pragma unroll
  for (int p = 0; p < 4; ++p) { const float t = x[p] - mu; s2 += t * t; }
  red[tid] = s2; __syncthreads();
  for (int off = 128; off > 0; off >>= 1) {
    if (tid < off) red[tid] += red[tid + off];
    __syncthreads();
  }
  const float rs = rsqrtf(red[0] * (1.f / DMODEL) + LN_EPS);
#pragma unroll
  for (int p = 0; p < 4; ++p) {
    const int c = tid + p * 256;
    out[base + c] = (x[p] - mu) * rs * gamma[c] + beta[c];
  }
}

// ---------------------------------------------------------------------------
extern "C" void kernel_launch(void* const* d_in, const int* in_sizes, int n_in,
                              void* d_out, int out_size, void* d_ws, size_t ws_size,
                              hipStream_t stream)
{
  const float* w     = (const float*)d_in[0];
  const float* r     = (const float*)d_in[1];
  const float* rwb   = (const float*)d_in[2];
  const float* rrb   = (const float*)d_in[3];
  const float* masks = (const float*)d_in[4];
  const float* Wqkv  = (const float*)d_in[5];
  const float* Wr    = (const float*)d_in[6];
  const float* mproj = (const float*)d_in[7];
  const float* Wo    = (const float*)d_in[8];
  const float* gam   = (const float*)d_in[9];
  const float* bet   = (const float*)d_in[10];
  float* out = (float*)d_out;

  float* ws = (float*)d_ws;
  // fp32-unit offsets; total 25,690,112 f = 102.8 MB
  // pool [0, 8388608): pre-gemm64 scratch, then Mh overlays all of it.
  __bf16* w_bf    = (__bf16*)(ws);                   // 2,097,152 f
  __bf16* Wqkv_bf = (__bf16*)(ws + 2097152);         //   655,360 f
  __bf16* r_bf    = (__bf16*)(ws + 2752512);         //   524,288 f
  __bf16* Wr_bf   = (__bf16*)(ws + 3276800);         //    65,536 f
  __bf16* Qw      = (__bf16*)(ws + 3342336);         //   262,144 f
  __bf16* Qr      = (__bf16*)(ws + 3604480);
  __bf16* Kb      = (__bf16*)(ws + 3866624);
  __bf16* Rb      = (__bf16*)(ws + 4128768);         //    65,536 f
  __bf16* Mh      = (__bf16*)(ws);                   // 8,388,608 f (post-gemm64)
  __bf16* AC_bf   = (__bf16*)(ws + 8388608);         // 4,194,304 f
  float*  ao      = ws + 8388608;                    // overlays AC (post-prep2)
  __bf16* BD_bf   = (__bf16*)(ws + 12582912);        // 4,194,304 f
  __bf16* Tg      = (__bf16*)(ws + 16777216);        // 4,194,304 f
  __bf16* Vt      = (__bf16*)(ws + 20971520);        // 2,097,152 f
  __bf16* av_bf   = (__bf16*)(ws + 23068672);        // 2,097,152 f
  __bf16* Wo_bf   = (__bf16*)(ws + 25165824);        //   524,288 f

  // 1) all input casts
  cast_all<<<3776, 256, 0, stream>>>(w, w_bf, Wqkv, Wqkv_bf, r, r_bf,
                                     Wr, Wr_bf, Wo, Wo_bf);
  // 2) QKV projection with fused Qw/Qr/Kb/Vt epilogue (no wh)
  gemm_qkv<<<dim3(10, 32), 256, 0, stream>>>(
      w_bf, Wqkv_bf, rwb, rrb, Qw, Qr, Kb, Vt);
  // 3) r projection -> Rb directly
  gemm_r<<<dim3(1, 8), 256, 0, stream>>>(r_bf, Wr_bf, Rb);
  // 4) AC/BD via MFMA
  gemm64_bf16<<<dim3(8, 8, 16), 256, 0, stream>>>(Qw, Qr, Kb, Rb, AC_bf, BD_bf);
  // 5) tshift + Mh (one dispatch; Mh overlays dead pool)
  prep2<<<3072, 256, 0, stream>>>(AC_bf, BD_bf, Tg, masks, mproj, Mh);
  // 6) attention: scores + softmax + PV (100% occupancy)
  attn5<<<dim3(64, 16, 4), 512, 0, stream>>>(Tg, Mh, Vt, av_bf);
  // 7) output projection -> fp32 ao (overlays dead AC)
  gemm_bf16<float><<<dim3(8, 32), 256, 0, stream>>>(
      av_bf, Wo_bf, ao, 1024, 1024, 1024, 1024);
  // 8) residual + LayerNorm
  ln_kernel<<<4096, 256, 0, stream>>>(w, ao, gam, bet, out);
}

// Round 7
// 267.234 us; speedup vs baseline: 1.3122x; 1.3122x over previous
//
#include <hip/hip_runtime.h>
#include <cstddef>
#include <cstdint>

#define QLEN   1024
#define SCALE  0.125f
#define LN_EPS 1e-5f
#define DMODEL 1024

typedef __bf16 bf16x8 __attribute__((ext_vector_type(8)));
typedef __bf16 bf16x4 __attribute__((ext_vector_type(4)));
typedef float  f32x4  __attribute__((ext_vector_type(4)));

__device__ __forceinline__ void load16_lds(const void* g, void* l) {
  __builtin_amdgcn_global_load_lds(
      (const __attribute__((address_space(1))) unsigned int*)g,
      (__attribute__((address_space(3))) unsigned int*)l, 16, 0, 0);
}

// ---------------------------------------------------------------------------
// One cast kernel for all five fp32->bf16 inputs (block-range partitioned).
// ---------------------------------------------------------------------------
__global__ __launch_bounds__(256) void cast_all(
    const float* __restrict__ w, __bf16* __restrict__ w_bf,
    const float* __restrict__ Wqkv, __bf16* __restrict__ Wqkv_bf,
    const float* __restrict__ r, __bf16* __restrict__ r_bf,
    const float* __restrict__ Wr, __bf16* __restrict__ Wr_bf,
    const float* __restrict__ Wo, __bf16* __restrict__ Wo_bf)
{
  int blk = blockIdx.x;
  const float* in; __bf16* out;
  if (blk < 2048)      { in = w;    out = w_bf;    }
  else if (blk < 2688) { blk -= 2048; in = Wqkv; out = Wqkv_bf; }
  else if (blk < 3200) { blk -= 2688; in = r;    out = r_bf;    }
  else if (blk < 3264) { blk -= 3200; in = Wr;   out = Wr_bf;   }
  else                 { blk -= 3264; in = Wo;   out = Wo_bf;   }
  const size_t i = ((size_t)blk * 256 + threadIdx.x) * 8;
  const float4 a = *(const float4*)&in[i];
  const float4 b = *(const float4*)&in[i + 4];
  bf16x8 o;
  o[0] = (__bf16)a.x; o[1] = (__bf16)a.y; o[2] = (__bf16)a.z; o[3] = (__bf16)a.w;
  o[4] = (__bf16)b.x; o[5] = (__bf16)b.y; o[6] = (__bf16)b.z; o[7] = (__bf16)b.w;
  *(bf16x8*)&out[i] = o;
}

// ---------------------------------------------------------------------------
// Merged projection GEMM, 128x64 tiles (12 KB LDS, 4 waves of 32x64):
//  blocks [0,640):  QKV: [4096,1280] = w_bf @ Wqkv_bf^T, scatter epilogue
//                   (Qw/Qr bias-folded, Kb, Vt transposed). wh never exists.
//  blocks [640,656): r:  [1024,128] = r_bf @ Wr_bf^T -> Rb[g][i][64].
// ---------------------------------------------------------------------------
__global__ __launch_bounds__(256) void gemm_proj(
    const __bf16* __restrict__ w_bf, const __bf16* __restrict__ Wqkv_bf,
    const __bf16* __restrict__ r_bf, const __bf16* __restrict__ Wr_bf,
    const float* __restrict__ rwb, const float* __restrict__ rrb,
    __bf16* __restrict__ Qw, __bf16* __restrict__ Qr,
    __bf16* __restrict__ Kb, __bf16* __restrict__ Vt,
    __bf16* __restrict__ Rb)
{
  __shared__ __bf16 Asl[128 * 32];
  __shared__ __bf16 Bsl[64 * 32];
  const int blk = blockIdx.x;
  const bool isR = blk >= 640;
  const __bf16 *A, *B;
  int m0, n0;
  if (!isR) { A = w_bf; B = Wqkv_bf; n0 = (blk % 20) * 64; m0 = (blk / 20) * 128; }
  else      { const int k = blk - 640; A = r_bf; B = Wr_bf;
              n0 = (k % 2) * 64; m0 = (k / 2) * 128; }

  const int tid = threadIdx.x, lane = tid & 63, wv = tid >> 6;
  const int lr = lane & 15, kq = lane >> 4;
  const int srow  = wv * 16 + (lane >> 2);
  const int sslot = lane & 3;
  const int sg0 = (sslot - ((srow >> 1) & 3)) & 3;
  const int sg1 = (sslot - (((srow + 64) >> 1) & 3)) & 3;
  const __bf16* Ag = A + (size_t)(m0 + srow) * 1024;
  const __bf16* Bg = B + (size_t)(n0 + srow) * 1024;
  __bf16* Al = &Asl[srow * 32 + sslot * 8];
  __bf16* Bl = &Bsl[srow * 32 + sslot * 8];

  f32x4 acc[2][4];
#pragma unroll
  for (int mt = 0; mt < 2; ++mt)
#pragma unroll
    for (int nt = 0; nt < 4; ++nt)
      acc[mt][nt] = (f32x4){0.f, 0.f, 0.f, 0.f};

  for (int k0 = 0; k0 < 1024; k0 += 32) {
    load16_lds(Ag + k0 + sg0 * 8, Al);
    load16_lds(Ag + (size_t)64 * 1024 + k0 + sg1 * 8, Al + 64 * 32);
    load16_lds(Bg + k0 + sg0 * 8, Bl);
    __syncthreads();
    bf16x8 af[2], bfr[4];
#pragma unroll
    for (int mt = 0; mt < 2; ++mt) {
      const int row = wv * 32 + mt * 16 + lr;
      af[mt] = *(const bf16x8*)&Asl[row * 32 + ((kq + (row >> 1)) & 3) * 8];
    }
#pragma unroll
    for (int nt = 0; nt < 4; ++nt) {
      const int row = nt * 16 + lr;
      bfr[nt] = *(const bf16x8*)&Bsl[row * 32 + ((kq + (row >> 1)) & 3) * 8];
    }
#pragma unroll
    for (int mt = 0; mt < 2; ++mt)
#pragma unroll
      for (int nt = 0; nt < 4; ++nt)
        acc[mt][nt] = __builtin_amdgcn_mfma_f32_16x16x32_bf16(
            af[mt], bfr[nt], acc[mt][nt], 0, 0, 0);
    __syncthreads();
  }

#pragma unroll
  for (int mt = 0; mt < 2; ++mt) {
    const int row0 = m0 + wv * 32 + mt * 16 + kq * 4;
#pragma unroll
    for (int nt = 0; nt < 4; ++nt) {
      const int gcol = n0 + nt * 16 + lr;
      const f32x4 c = acc[mt][nt];
      if (isR) {
        const int g = gcol >> 6, d = gcol & 63;
#pragma unroll
        for (int reg = 0; reg < 4; ++reg)
          Rb[(size_t)g * 65536 + (size_t)(row0 + reg) * 64 + d] = (__bf16)c[reg];
      } else if (gcol < 128) {       // Q
        const int g = gcol >> 6, d = gcol & 63;
        const float bw = rwb[gcol], br = rrb[gcol];
#pragma unroll
        for (int reg = 0; reg < 4; ++reg) {
          const int row = row0 + reg, i = row >> 2, b = row & 3;
          const size_t o = (size_t)(b * 2 + g) * 65536 + (size_t)i * 64 + d;
          Qw[o] = (__bf16)(c[reg] + bw);
          Qr[o] = (__bf16)(c[reg] + br);
        }
      } else if (gcol < 256) {       // K
        const int lc = gcol - 128, g = lc >> 6, d = lc & 63;
#pragma unroll
        for (int reg = 0; reg < 4; ++reg) {
          const int row = row0 + reg, i = row >> 2, b = row & 3;
          Kb[(size_t)(b * 2 + g) * 65536 + (size_t)i * 64 + d] = (__bf16)c[reg];
        }
      } else {                       // V -> transposed Vt
        const int lc = gcol - 256, h = lc >> 6, d = lc & 63;
#pragma unroll
        for (int reg = 0; reg < 4; ++reg) {
          const int row = row0 + reg, i = row >> 2, b = row & 3;
          Vt[((size_t)((b * 16 + h) * 64 + d)) * 1024 + i] = (__bf16)c[reg];
        }
      }
    }
  }
}

// ---------------------------------------------------------------------------
// Wo projection, 128x64 tiles: ao[4096,1024] = av_bf @ Wo_bf^T (fp32 out).
// grid (16, 32) = 512 blocks.
// ---------------------------------------------------------------------------
__global__ __launch_bounds__(256) void gemm_wo(
    const __bf16* __restrict__ A, const __bf16* __restrict__ B,
    float* __restrict__ C)
{
  __shared__ __bf16 Asl[128 * 32];
  __shared__ __bf16 Bsl[64 * 32];
  const int m0 = blockIdx.y * 128, n0 = blockIdx.x * 64;
  const int tid = threadIdx.x, lane = tid & 63, wv = tid >> 6;
  const int lr = lane & 15, kq = lane >> 4;
  const int srow  = wv * 16 + (lane >> 2);
  const int sslot = lane & 3;
  const int sg0 = (sslot - ((srow >> 1) & 3)) & 3;
  const int sg1 = (sslot - (((srow + 64) >> 1) & 3)) & 3;
  const __bf16* Ag = A + (size_t)(m0 + srow) * 1024;
  const __bf16* Bg = B + (size_t)(n0 + srow) * 1024;
  __bf16* Al = &Asl[srow * 32 + sslot * 8];
  __bf16* Bl = &Bsl[srow * 32 + sslot * 8];

  f32x4 acc[2][4];
#pragma unroll
  for (int mt = 0; mt < 2; ++mt)
#pragma unroll
    for (int nt = 0; nt < 4; ++nt)
      acc[mt][nt] = (f32x4){0.f, 0.f, 0.f, 0.f};

  for (int k0 = 0; k0 < 1024; k0 += 32) {
    load16_lds(Ag + k0 + sg0 * 8, Al);
    load16_lds(Ag + (size_t)64 * 1024 + k0 + sg1 * 8, Al + 64 * 32);
    load16_lds(Bg + k0 + sg0 * 8, Bl);
    __syncthreads();
    bf16x8 af[2], bfr[4];
#pragma unroll
    for (int mt = 0; mt < 2; ++mt) {
      const int row = wv * 32 + mt * 16 + lr;
      af[mt] = *(const bf16x8*)&Asl[row * 32 + ((kq + (row >> 1)) & 3) * 8];
    }
#pragma unroll
    for (int nt = 0; nt < 4; ++nt) {
      const int row = nt * 16 + lr;
      bfr[nt] = *(const bf16x8*)&Bsl[row * 32 + ((kq + (row >> 1)) & 3) * 8];
    }
#pragma unroll
    for (int mt = 0; mt < 2; ++mt)
#pragma unroll
      for (int nt = 0; nt < 4; ++nt)
        acc[mt][nt] = __builtin_amdgcn_mfma_f32_16x16x32_bf16(
            af[mt], bfr[nt], acc[mt][nt], 0, 0, 0);
    __syncthreads();
  }

#pragma unroll
  for (int mt = 0; mt < 2; ++mt) {
    const int row0 = m0 + wv * 32 + mt * 16 + kq * 4;
#pragma unroll
    for (int nt = 0; nt < 4; ++nt) {
      const int col = n0 + nt * 16 + lr;
      const f32x4 c = acc[mt][nt];
#pragma unroll
      for (int reg = 0; reg < 4; ++reg)
        C[(size_t)(row0 + reg) * 1024 + col] = c[reg];
    }
  }
}

// ---------------------------------------------------------------------------
// Batched K=64 bf16 MFMA GEMM for AC/BD. Rb indexed by g only.
// ---------------------------------------------------------------------------
__global__ __launch_bounds__(256) void gemm64_bf16(
    const __bf16* __restrict__ Qw, const __bf16* __restrict__ Qr,
    const __bf16* __restrict__ Kb, const __bf16* __restrict__ Rb,
    __bf16* __restrict__ AC, __bf16* __restrict__ BDo)
{
  __shared__ __bf16 Asl[128 * 64];
  __shared__ __bf16 Bsl[128 * 64];
  const int tid = threadIdx.x, lane = tid & 63, wv = tid >> 6;
  const int which = blockIdx.z & 1, bat = blockIdx.z >> 1;
  const int m0 = blockIdx.y * 128, n0 = blockIdx.x * 128;
  const __bf16* Ap = (which ? Qr : Qw) + (size_t)bat * 65536;
  const __bf16* Bp = which ? (Rb + (size_t)(bat & 1) * 65536)
                           : (Kb + (size_t)bat * 65536);
  __bf16* Cp = (which ? BDo : AC) + (size_t)bat * 1048576;

#pragma unroll
  for (int p = 0; p < 4; ++p) {
    const int row = wv * 32 + p * 8 + (lane >> 3);
    const int s = lane & 7;
    const int gc = (s - (row & 7)) & 7;
    load16_lds(Ap + (size_t)(m0 + row) * 64 + gc * 8, &Asl[row * 64 + s * 8]);
    load16_lds(Bp + (size_t)(n0 + row) * 64 + gc * 8, &Bsl[row * 64 + s * 8]);
  }
  __syncthreads();

  const int lr = lane & 15, kq = lane >> 4;
  const int wm = (wv >> 1) * 64, wn = (wv & 1) * 64;
  f32x4 acc[4][4];
#pragma unroll
  for (int mt = 0; mt < 4; ++mt)
#pragma unroll
    for (int nt = 0; nt < 4; ++nt)
      acc[mt][nt] = (f32x4){0.f, 0.f, 0.f, 0.f};

#pragma unroll
  for (int ks = 0; ks < 2; ++ks) {
    const int c = ks * 4 + kq;
    bf16x8 af[4], bfr[4];
#pragma unroll
    for (int mt = 0; mt < 4; ++mt) {
      const int row = wm + mt * 16 + lr;
      af[mt] = *(const bf16x8*)&Asl[row * 64 + ((c + (row & 7)) & 7) * 8];
    }
#pragma unroll
    for (int nt = 0; nt < 4; ++nt) {
      const int row = wn + nt * 16 + lr;
      bfr[nt] = *(const bf16x8*)&Bsl[row * 64 + ((c + (row & 7)) & 7) * 8];
    }
#pragma unroll
    for (int mt = 0; mt < 4; ++mt)
#pragma unroll
      for (int nt = 0; nt < 4; ++nt)
        acc[mt][nt] = __builtin_amdgcn_mfma_f32_16x16x32_bf16(
            af[mt], bfr[nt], acc[mt][nt], 0, 0, 0);
  }

#pragma unroll
  for (int mt = 0; mt < 4; ++mt) {
    const int row0 = m0 + wm + mt * 16 + kq * 4;
#pragma unroll
    for (int nt = 0; nt < 4; ++nt) {
      const int col = n0 + wn + nt * 16 + lr;
      const f32x4 cc = acc[mt][nt];
#pragma unroll
      for (int reg = 0; reg < 4; ++reg)
        Cp[(size_t)(row0 + reg) * 1024 + col] = (__bf16)cc[reg];
    }
  }
}

// ---------------------------------------------------------------------------
// prep2: blocks [0,2048) = tshift (T = (AC+BDshift)*SCALE),
//        blocks [2048,3072) = per-head mixed masks Mh.
// ---------------------------------------------------------------------------
__global__ __launch_bounds__(256) void prep2(
    const __bf16* __restrict__ AC, const __bf16* __restrict__ BDm,
    __bf16* __restrict__ Tg,
    const float* __restrict__ masks, const float* __restrict__ mproj,
    __bf16* __restrict__ Mh)
{
  const int tid = threadIdx.x;
  if (blockIdx.x < 2048) {
    const int blk = blockIdx.x;
    const size_t bg = blk >> 8;
    const int i = (blk & 255) * 4 + (tid >> 6);
    const int lane = tid & 63;
    const __bf16* ACr = AC + bg * 1048576 + (size_t)i * 1024;
    const __bf16* BDb = BDm + bg * 1048576;
    __bf16* Tr = Tg + bg * 1048576 + (size_t)i * 1024;
#pragma unroll
    for (int c2 = 0; c2 < 4; ++c2) {
      const int j0 = c2 * 256 + lane * 4;
      const bf16x4 ac4 = *(const bf16x4*)&ACr[j0];
      bf16x4 o;
#pragma unroll
      for (int k = 0; k < 4; ++k) {
        const int j = j0 + k;
        float bd;
        if (j <= i)          bd = (float)BDb[(size_t)i * 1024 + (j + QLEN - 1 - i)];
        else if (j == i + 1) bd = 0.f;
        else                 bd = (float)BDb[(size_t)(i + 1) * 1024 + (j - i - 2)];
        o[k] = (__bf16)(((float)ac4[k] + bd) * SCALE);
      }
      *(bf16x4*)&Tr[j0] = o;
    }
  } else {
    const int blk = blockIdx.x - 2048;
    const size_t ij0 = ((size_t)blk * 256 + tid) * 4;
    const float4 a = *(const float4*)&masks[ij0 * 3];
    const float4 b = *(const float4*)&masks[ij0 * 3 + 4];
    const float4 c = *(const float4*)&masks[ij0 * 3 + 8];
    const float m0[4] = {a.x, a.w, b.z, c.y};
    const float m1[4] = {a.y, b.x, b.w, c.z};
    const float m2[4] = {a.z, b.y, c.x, c.w};
#pragma unroll
    for (int h = 0; h < 16; ++h) {
      const float p0 = mproj[h], p1 = mproj[16 + h], p2 = mproj[32 + h];
      bf16x4 o;
#pragma unroll
      for (int k = 0; k < 4; ++k)
        o[k] = (__bf16)(m0[k] * p0 + m1[k] * p1 + m2[k] * p2);
      *(bf16x4*)&Mh[(size_t)h * 1048576 + ij0] = o;
    }
  }
}

// ---------------------------------------------------------------------------
// attn6: attn4 structure (256 thr, 4 waves, 16 d-cols/wave, no duplication)
// + 4 independent PV accumulators (dependent-MFMA chain 32 -> 8).
// grid (64, 16, 4), LDS 32 KB.
// ---------------------------------------------------------------------------
__global__ __launch_bounds__(256) void attn6(
    const __bf16* __restrict__ Tg, const __bf16* __restrict__ Mh,
    const __bf16* __restrict__ Vt, __bf16* __restrict__ av)
{
  __shared__ __bf16 P[16 * 1024];
  __shared__ float rinvS[16];
  const int tid = threadIdx.x;
  const int i0 = blockIdx.x * 16;
  const int h = blockIdx.y, b = blockIdx.z;
  const int g = h >> 3;
  const size_t bg = (size_t)(b * 2 + g);
  const int r = tid >> 4, li = tid & 15;
  const __bf16* Trow = Tg + bg * 1048576 + (size_t)(i0 + r) * 1024;
  const __bf16* Mrow = Mh + (size_t)h * 1048576 + (size_t)(i0 + r) * 1024;

  // single-pass scores: no max subtraction (|s| <= ~8 analytically)
  float sum = 0.f;
#pragma unroll
  for (int q = 0; q < 8; ++q) {
    const int jb = q * 128 + li * 8;
    const bf16x8 t8 = *(const bf16x8*)&Trow[jb];
    const bf16x8 m8 = *(const bf16x8*)&Mrow[jb];
    const int csw = (jb >> 3) ^ (r & 7);
    bf16x8 p8;
#pragma unroll
    for (int k = 0; k < 8; ++k) {
      const float e = __expf((float)t8[k] * (float)m8[k]);
      sum += e;
      p8[k] = (__bf16)e;
    }
    *(bf16x8*)&P[r * 1024 + csw * 8] = p8;
  }
  sum += __shfl_xor(sum, 1);
  sum += __shfl_xor(sum, 2);
  sum += __shfl_xor(sum, 4);
  sum += __shfl_xor(sum, 8);
  if (li == 0) rinvS[r] = 1.f / sum;
  __syncthreads();

  // PV: wave wv covers d in [wv*16, wv*16+16); 4 independent acc chains
  const int lane = tid & 63, wv = tid >> 6;
  const int m = lane & 15, kq = lane >> 4;
  const __bf16* vbase = Vt + ((size_t)((b * 16 + h) * 64 + wv * 16 + m)) * 1024 + kq * 8;
  f32x4 acc[4];
#pragma unroll
  for (int u = 0; u < 4; ++u) acc[u] = (f32x4){0.f, 0.f, 0.f, 0.f};
#pragma unroll 2
  for (int ks = 0; ks < 32; ks += 4) {
#pragma unroll
    for (int u = 0; u < 4; ++u) {
      const int c = (ks + u) * 4 + kq;
      const bf16x8 a = *(const bf16x8*)&P[m * 1024 + ((c ^ (m & 7)) << 3)];
      const bf16x8 vv = *(const bf16x8*)&vbase[(ks + u) * 32];
      acc[u] = __builtin_amdgcn_mfma_f32_16x16x32_bf16(a, vv, acc[u], 0, 0, 0);
    }
  }
  const f32x4 accf = (acc[0] + acc[1]) + (acc[2] + acc[3]);
#pragma unroll
  for (int reg = 0; reg < 4; ++reg) {
    const int row = kq * 4 + reg;
    av[((size_t)(i0 + row) * 4 + b) * 1024 + h * 64 + wv * 16 + m] =
        (__bf16)(accf[reg] * rinvS[row]);
  }
}

// ---------------------------------------------------------------------------
// residual + LayerNorm
// ---------------------------------------------------------------------------
__global__ __launch_bounds__(256) void ln_kernel(
    const float* __restrict__ w, const float* __restrict__ ao,
    const float* __restrict__ gamma, const float* __restrict__ beta,
    float* __restrict__ out)
{
  const int tid = threadIdx.x;
  const size_t base = (size_t)blockIdx.x * DMODEL;
  __shared__ float red[256];
  float x[4];
  float s = 0.f;
#pragma unroll
  for (int p = 0; p < 4; ++p) {
    const int c = tid + p * 256;
    x[p] = w[base + c] + ao[base + c];
    s += x[p];
  }
  red[tid] = s; __syncthreads();
  for (int off = 128; off > 0; off >>= 1) {
    if (tid < off) red[tid] += red[tid + off];
    __syncthreads();
  }
  const float mu = red[0] * (1.f / DMODEL);
  __syncthreads();
  float s2 = 0.f;
#pragma unroll
  for (int p = 0; p < 4; ++p) { const float t = x[p] - mu; s2 += t * t; }
  red[tid] = s2; __syncthreads();
  for (int off = 128; off > 0; off >>= 1) {
    if (tid < off) red[tid] += red[tid + off];
    __syncthreads();
  }
  const float rs = rsqrtf(red[0] * (1.f / DMODEL) + LN_EPS);
#pragma unroll
  for (int p = 0; p < 4; ++p) {
    const int c = tid + p * 256;
    out[base + c] = (x[p] - mu) * rs * gamma[c] + beta[c];
  }
}

// ---------------------------------------------------------------------------
extern "C" void kernel_launch(void* const* d_in, const int* in_sizes, int n_in,
                              void* d_out, int out_size, void* d_ws, size_t ws_size,
                              hipStream_t stream)
{
  const float* w     = (const float*)d_in[0];
  const float* r     = (const float*)d_in[1];
  const float* rwb   = (const float*)d_in[2];
  const float* rrb   = (const float*)d_in[3];
  const float* masks = (const float*)d_in[4];
  const float* Wqkv  = (const float*)d_in[5];
  const float* Wr    = (const float*)d_in[6];
  const float* mproj = (const float*)d_in[7];
  const float* Wo    = (const float*)d_in[8];
  const float* gam   = (const float*)d_in[9];
  const float* bet   = (const float*)d_in[10];
  float* out = (float*)d_out;

  float* ws = (float*)d_ws;
  // fp32-unit offsets; total 25,690,112 f = 102.8 MB
  __bf16* w_bf    = (__bf16*)(ws);                   // 2,097,152 f
  __bf16* Wqkv_bf = (__bf16*)(ws + 2097152);         //   655,360 f
  __bf16* r_bf    = (__bf16*)(ws + 2752512);         //   524,288 f
  __bf16* Wr_bf   = (__bf16*)(ws + 3276800);         //    65,536 f
  __bf16* Qw      = (__bf16*)(ws + 3342336);         //   262,144 f
  __bf16* Qr      = (__bf16*)(ws + 3604480);
  __bf16* Kb      = (__bf16*)(ws + 3866624);
  __bf16* Rb      = (__bf16*)(ws + 4128768);         //    65,536 f
  __bf16* Mh      = (__bf16*)(ws);                   // 8,388,608 f (post-gemm64)
  __bf16* AC_bf   = (__bf16*)(ws + 8388608);         // 4,194,304 f
  float*  ao      = ws + 8388608;                    // overlays AC (post-prep2)
  __bf16* BD_bf   = (__bf16*)(ws + 12582912);        // 4,194,304 f
  __bf16* Tg      = (__bf16*)(ws + 16777216);        // 4,194,304 f
  __bf16* Vt      = (__bf16*)(ws + 20971520);        // 2,097,152 f
  __bf16* av_bf   = (__bf16*)(ws + 23068672);        // 2,097,152 f
  __bf16* Wo_bf   = (__bf16*)(ws + 25165824);        //   524,288 f

  // 1) all input casts
  cast_all<<<3776, 256, 0, stream>>>(w, w_bf, Wqkv, Wqkv_bf, r, r_bf,
                                     Wr, Wr_bf, Wo, Wo_bf);
  // 2) merged QKV + r projections (fused epilogues; no wh)
  gemm_proj<<<656, 256, 0, stream>>>(
      w_bf, Wqkv_bf, r_bf, Wr_bf, rwb, rrb, Qw, Qr, Kb, Vt, Rb);
  // 3) AC/BD via MFMA
  gemm64_bf16<<<dim3(8, 8, 16), 256, 0, stream>>>(Qw, Qr, Kb, Rb, AC_bf, BD_bf);
  // 4) tshift + Mh (one dispatch; Mh overlays dead pool)
  prep2<<<3072, 256, 0, stream>>>(AC_bf, BD_bf, Tg, masks, mproj, Mh);
  // 5) attention: scores + softmax + PV (4-way ILP MFMA chains)
  attn6<<<dim3(64, 16, 4), 256, 0, stream>>>(Tg, Mh, Vt, av_bf);
  // 6) output projection -> fp32 ao (overlays dead AC)
  gemm_wo<<<dim3(16, 32), 256, 0, stream>>>(av_bf, Wo_bf, ao);
  // 7) residual + LayerNorm
  ln_kernel<<<4096, 256, 0, stream>>>(w, ao, gam, bet, out);
}